// Round 3
// baseline (1918.494 us; speedup 1.0000x reference)
//
#include <hip/hip_runtime.h>
#include <hip/hip_bf16.h>
#include <stdint.h>

typedef __attribute__((ext_vector_type(8))) _Float16 half8;
typedef __attribute__((ext_vector_type(4))) float f32x4;
typedef __attribute__((ext_vector_type(4))) unsigned short us4;
typedef __attribute__((ext_vector_type(8))) unsigned short us8;

#define N_TOK 8192
#define DIM   1024
#define HDIM  2048
#define ODIM  1024

__device__ __forceinline__ unsigned short f2h(float f) {
  _Float16 h = (_Float16)f;            // v_cvt_f16_f32, RNE
  union { _Float16 h; unsigned short u; } c; c.h = h; return c.u;
}

__device__ __forceinline__ void gload_lds16(const void* g, void* l) {
  __builtin_amdgcn_global_load_lds(
      (const __attribute__((address_space(1))) unsigned int*)g,
      (__attribute__((address_space(3))) unsigned int*)l, 16, 0, 0);
}

// ---------------------------------------------------------------------------
// fp16 GEMM: C = A[M,K] * B^T[N,K]  (both row-major, leading dim K)
// EPI=1: Hout = fp16(relu(C + bias[col]))    EPI=2: Y[row,col] += Wg[row*8+e]*C
// 128x128 tile, BK=32, 4 waves (2x2) of 64x64, mfma_f32_16x16x32_f16.
// LDS granule g = kq*128 + row  (16B granule = 8 fp16 of k); staged via
// global_load_lds width-16 (wave-uniform LDS base + lane*16). Fragment reads
// are lane-consecutive 16B granules => <=2-way banks (free, m136).
// XCD-aware chunked swizzle (T1): bijective since nwg % 8 == 0 here.
// ---------------------------------------------------------------------------
template <int EPI>
__global__ __launch_bounds__(256) void gemm_kernel(
    const unsigned short* __restrict__ A, const unsigned short* __restrict__ B,
    int M, int N, int K,
    const float* __restrict__ bias, unsigned short* __restrict__ Hout,
    const float* __restrict__ Wg, int e, float* __restrict__ Y)
{
  __shared__ half8 ldsA[2][512];
  __shared__ half8 ldsB[2][512];
  const int lane = threadIdx.x & 63, wid = threadIdx.x >> 6;
  const int wr = wid >> 1, wc = wid & 1;

  // T1: XCD swizzle. nwg = gridDim.x*gridDim.y is a multiple of 8.
  const int nwg = gridDim.x * gridDim.y;
  const int orig = blockIdx.y * gridDim.x + blockIdx.x;
  const int qq = nwg >> 3;
  const int swz = (orig & 7) * qq + (orig >> 3);
  const int bx = swz % gridDim.x, by = swz / gridDim.x;
  const int rowbase = by * 128, colbase = bx * 128;

  f32x4 acc[4][4];
#pragma unroll
  for (int m = 0; m < 4; ++m)
#pragma unroll
    for (int n = 0; n < 4; ++n) acc[m][n] = f32x4{0.f, 0.f, 0.f, 0.f};

  auto stage = [&](int buf, int ktile) {
#pragma unroll
    for (int i = 0; i < 4; ++i) {
      const int c = wid * 4 + i;           // 16 chunks: 8 A + 8 B, each 1KB
      const int cc = c & 7, kq = cc >> 1, half = cc & 1;
      const int koff = ktile * 32 + kq * 8;
      if (c < 8)
        gload_lds16(A + (size_t)(rowbase + half * 64 + lane) * K + koff,
                    &ldsA[buf][kq * 128 + half * 64]);
      else
        gload_lds16(B + (size_t)(colbase + half * 64 + lane) * K + koff,
                    &ldsB[buf][kq * 128 + half * 64]);
    }
  };

  const int KT = K >> 5;
  stage(0, 0);
  for (int kt = 0; kt < KT; ++kt) {
    const int buf = kt & 1;
    __syncthreads();                      // drains vmcnt+lgkmcnt for buf
    if (kt + 1 < KT) stage(buf ^ 1, kt + 1);

    half8 af[4], bfr[4];
    const int kqo = (lane >> 4) * 128;
    const int rA = wr * 64 + (lane & 15);
    const int rB = wc * 64 + (lane & 15);
#pragma unroll
    for (int m = 0; m < 4; ++m) af[m] = ldsA[buf][kqo + rA + m * 16];
#pragma unroll
    for (int n = 0; n < 4; ++n) bfr[n] = ldsB[buf][kqo + rB + n * 16];
#pragma unroll
    for (int m = 0; m < 4; ++m)
#pragma unroll
      for (int n = 0; n < 4; ++n)
        acc[m][n] = __builtin_amdgcn_mfma_f32_16x16x32_f16(af[m], bfr[n], acc[m][n], 0, 0, 0);
  }

  const int r0 = rowbase + wr * 64, c0 = colbase + wc * 64;
  if (EPI == 1) {
#pragma unroll
    for (int n = 0; n < 4; ++n) {
      const int col = c0 + n * 16 + (lane & 15);
      const float bv = bias[col];
#pragma unroll
      for (int m = 0; m < 4; ++m)
#pragma unroll
        for (int r = 0; r < 4; ++r) {
          const int row = r0 + m * 16 + (lane >> 4) * 4 + r;
          float v = acc[m][n][r] + bv;
          v = v > 0.f ? v : 0.f;
          Hout[(size_t)row * N + col] = f2h(v);
        }
    }
  } else {
#pragma unroll
    for (int m = 0; m < 4; ++m)
#pragma unroll
      for (int r = 0; r < 4; ++r) {
        const int row = r0 + m * 16 + (lane >> 4) * 4 + r;
        const float wv = Wg[row * 8 + e];
#pragma unroll
        for (int n = 0; n < 4; ++n) {
          const int col = c0 + n * 16 + (lane & 15);
          const size_t idx = (size_t)row * N + col;
          Y[idx] += wv * acc[m][n][r];
        }
      }
  }
}

// ---------------------------------------------------------------------------
// Gating / ph-match / clarity: one wave per token, fp32 throughout.
// Also emits the fp16 cast of x (fused — x is already streaming through).
// ---------------------------------------------------------------------------
__global__ __launch_bounds__(256) void gating_kernel(
    const float* __restrict__ x,
    const float* __restrict__ gate_w, const float* __restrict__ gate_b,
    const float* __restrict__ ph_w1, const float* __restrict__ ph_b1,
    const float* __restrict__ ph_w2, const float* __restrict__ ph_b2,
    const float* __restrict__ cl_w1, const float* __restrict__ cl_b1,
    const float* __restrict__ cl_w2, const float* __restrict__ cl_b2,
    const float* __restrict__ sigs,
    unsigned short* __restrict__ xh,
    float* __restrict__ eff_o,
    float* __restrict__ pclar, float* __restrict__ pP)
{
  const int lane = threadIdx.x & 63, wid = threadIdx.x >> 6;
  const int tok = blockIdx.x * 4 + wid;

  float g[8], p1[32], c1[16];
#pragma unroll
  for (int i = 0; i < 8; ++i) g[i] = 0.f;
#pragma unroll
  for (int i = 0; i < 32; ++i) p1[i] = 0.f;
#pragma unroll
  for (int i = 0; i < 16; ++i) c1[i] = 0.f;

  const f32x4* x4 = (const f32x4*)(x + (size_t)tok * DIM);
  us4* xh4 = (us4*)(xh + (size_t)tok * DIM);
#pragma unroll
  for (int d0 = 0; d0 < 4; ++d0) {
    const f32x4 xv = x4[d0 * 64 + lane];
    us4 ov;
#pragma unroll
    for (int j = 0; j < 4; ++j) {
      const int d = (d0 * 64 + lane) * 4 + j;
      const float xd = xv[j];
      ov[j] = f2h(xd);
      const f32x4* gw = (const f32x4*)(gate_w + d * 8);
#pragma unroll
      for (int q = 0; q < 2; ++q) { const f32x4 w = gw[q];
#pragma unroll
        for (int r = 0; r < 4; ++r) g[q * 4 + r] += xd * w[r]; }
      const f32x4* pw = (const f32x4*)(ph_w1 + d * 32);
#pragma unroll
      for (int q = 0; q < 8; ++q) { const f32x4 w = pw[q];
#pragma unroll
        for (int r = 0; r < 4; ++r) p1[q * 4 + r] += xd * w[r]; }
      const f32x4* cw = (const f32x4*)(cl_w1 + d * 16);
#pragma unroll
      for (int q = 0; q < 4; ++q) { const f32x4 w = cw[q];
#pragma unroll
        for (int r = 0; r < 4; ++r) c1[q * 4 + r] += xd * w[r]; }
    }
    xh4[d0 * 64 + lane] = ov;
  }
  // wave64 butterfly reductions
#pragma unroll
  for (int i = 0; i < 8; ++i)
#pragma unroll
    for (int s = 0; s < 6; ++s) g[i] += __shfl_xor(g[i], 1 << s);
#pragma unroll
  for (int i = 0; i < 32; ++i)
#pragma unroll
    for (int s = 0; s < 6; ++s) p1[i] += __shfl_xor(p1[i], 1 << s);
#pragma unroll
  for (int i = 0; i < 16; ++i)
#pragma unroll
    for (int s = 0; s < 6; ++s) c1[i] += __shfl_xor(c1[i], 1 << s);

  // softmax((scores+b)/e)
  float sc[8]; float mx = -1e30f;
#pragma unroll
  for (int k = 0; k < 8; ++k) { sc[k] = (g[k] + gate_b[k]) / 2.718281828459045f; mx = fmaxf(mx, sc[k]); }
  float ex[8]; float sum = 0.f;
#pragma unroll
  for (int k = 0; k < 8; ++k) { ex[k] = expf(sc[k] - mx); sum += ex[k]; }
  float pe[8];
#pragma unroll
  for (int k = 0; k < 8; ++k) pe[k] = ex[k] / sum;

  // ph feature -> normalize -> match
  float rh[32];
#pragma unroll
  for (int h = 0; h < 32; ++h) { const float v = p1[h] + ph_b1[h]; rh[h] = v > 0.f ? v : 0.f; }
  float feat[16];
#pragma unroll
  for (int q = 0; q < 16; ++q) {
    float f = ph_b2[q];
#pragma unroll
    for (int h = 0; h < 32; ++h) f += rh[h] * ph_w2[h * 16 + q];
    feat[q] = f;
  }
  float nn = 0.f;
#pragma unroll
  for (int q = 0; q < 16; ++q) nn += feat[q] * feat[q];
  const float den = fmaxf(sqrtf(nn), 1e-12f);
#pragma unroll
  for (int q = 0; q < 16; ++q) feat[q] = feat[q] / den;

  float eff[8];
#pragma unroll
  for (int k = 0; k < 8; ++k) {
    float s2 = 0.f;
#pragma unroll
    for (int q = 0; q < 16; ++q) { const float sv = sigs[k * 16 + q]; s2 += sv * sv; }
    const float sden = fmaxf(sqrtf(s2), 1e-12f);
    float dot = 0.f;
#pragma unroll
    for (int q = 0; q < 16; ++q) dot += feat[q] * (sigs[k * 16 + q] / sden);
    eff[k] = pe[k] * ((dot + 1.0f) / 2.0f);
  }

  // clarity
  float z = cl_b2[0];
#pragma unroll
  for (int c = 0; c < 16; ++c) { float v = c1[c] + cl_b1[c]; v = v > 0.f ? v : 0.f; z += v * cl_w2[c]; }
  const float clar = 1.0f / (1.0f + expf(-z));

  if (lane == 0) {
#pragma unroll
    for (int k = 0; k < 8; ++k) eff_o[tok * 8 + k] = eff[k];
  }
  __shared__ float shc[4];
  __shared__ float shP[4][8];
  if (lane == 0) { shc[wid] = clar;
#pragma unroll
    for (int k = 0; k < 8; ++k) shP[wid][k] = pe[k]; }
  __syncthreads();
  if (threadIdx.x == 0) {
    pclar[blockIdx.x] = shc[0] + shc[1] + shc[2] + shc[3];
#pragma unroll
    for (int k = 0; k < 8; ++k)
      pP[blockIdx.x * 8 + k] = shP[0][k] + shP[1][k] + shP[2][k] + shP[3][k];
  }
}

// ---------------------------------------------------------------------------
// k + top-k mask + weight normalization + active counts
// ---------------------------------------------------------------------------
__global__ __launch_bounds__(256) void weights_kernel(
    const float* __restrict__ eff_i, const float* __restrict__ pclar,
    float* __restrict__ wout, int* __restrict__ f_part)
{
  __shared__ float red[256];
  __shared__ int cnt[8];
  __shared__ int ksh;
  const int tid = threadIdx.x;
  float s = 0.f;
  for (int i = tid; i < 2048; i += 256) s += pclar[i];
  red[tid] = s; __syncthreads();
  for (int off = 128; off > 0; off >>= 1) { if (tid < off) red[tid] += red[tid + off]; __syncthreads(); }
  if (tid == 0) {
    const float mean_na = 8.0f - 6.0f * (red[0] / 8192.0f);
    int k = (int)floorf(mean_na + 0.5f);
    ksh = k < 2 ? 2 : (k > 8 ? 8 : k);
  }
  if (tid < 8) cnt[tid] = 0;
  __syncthreads();
  const int k = ksh;
  const int t = blockIdx.x * 256 + tid;
  const f32x4* ep = (const f32x4*)(eff_i + t * 8);
  const f32x4 ea = ep[0], eb = ep[1];
  const float ef[8] = {ea[0], ea[1], ea[2], ea[3], eb[0], eb[1], eb[2], eb[3]};
  float w[8]; float wsum = 0.f; int act[8];
#pragma unroll
  for (int e2 = 0; e2 < 8; ++e2) {
    int r = 0;
#pragma unroll
    for (int j = 0; j < 8; ++j) r += (int)((ef[j] > ef[e2]) || ((j < e2) && (ef[j] == ef[e2])));
    const float we = (r < k) ? ef[e2] : 0.f;
    w[e2] = we; wsum += we; act[e2] = we > 0.f ? 1 : 0;
  }
  const float dn = wsum + 1e-8f;
#pragma unroll
  for (int e2 = 0; e2 < 8; ++e2) wout[t * 8 + e2] = w[e2] / dn;
#pragma unroll
  for (int e2 = 0; e2 < 8; ++e2) if (act[e2]) atomicAdd(&cnt[e2], 1);
  __syncthreads();
  if (tid < 8) f_part[blockIdx.x * 8 + tid] = cnt[tid];
}

__global__ __launch_bounds__(256) void lb_kernel(
    const float* __restrict__ pP, const int* __restrict__ f_part, float* __restrict__ lbout)
{
  __shared__ float red[256];
  __shared__ float Ps[8], Fs[8];
  const int tid = threadIdx.x;
  for (int e2 = 0; e2 < 8; ++e2) {
    float s = 0.f;
    for (int i = tid; i < 2048; i += 256) s += pP[i * 8 + e2];
    red[tid] = s; __syncthreads();
    for (int off = 128; off > 0; off >>= 1) { if (tid < off) red[tid] += red[tid + off]; __syncthreads(); }
    if (tid == 0) Ps[e2] = red[0];
    __syncthreads();
    red[tid] = (tid < 32) ? (float)f_part[tid * 8 + e2] : 0.f;
    __syncthreads();
    for (int off = 128; off > 0; off >>= 1) { if (tid < off) red[tid] += red[tid + off]; __syncthreads(); }
    if (tid == 0) Fs[e2] = red[0];
    __syncthreads();
  }
  if (tid == 0) {
    float lb = 0.f;
    for (int e2 = 0; e2 < 8; ++e2) lb += (Fs[e2] / 8192.0f) * (Ps[e2] / 8192.0f);
    lbout[0] = 0.01f * 8.0f * lb;
  }
}

__global__ __launch_bounds__(256) void yinit_kernel(
    const float* __restrict__ w, const float* __restrict__ b2, float* __restrict__ y)
{
  const int idx = blockIdx.x * 256 + threadIdx.x;   // over N*O/4
  const int n = idx >> 8, o4 = idx & 255;
  const f32x4* bv = (const f32x4*)b2;
  f32x4 a = f32x4{0.f, 0.f, 0.f, 0.f};
  const float* wr = w + n * 8;
#pragma unroll
  for (int e2 = 0; e2 < 8; ++e2) a += wr[e2] * bv[e2 * 256 + o4];
  ((f32x4*)y)[idx] = a;
}

// per-expert [R,C] f32 -> [C,R] fp16
__global__ __launch_bounds__(256) void transpose_kernel(
    const float* __restrict__ in, unsigned short* __restrict__ out, int R, int C)
{
  __shared__ __align__(16) unsigned short t[64][72];
  const float* ip = in + (size_t)blockIdx.z * R * C;
  unsigned short* op = out + (size_t)blockIdx.z * R * C;
  const int r0 = blockIdx.y * 64, c0 = blockIdx.x * 64;
  const int tr = threadIdx.x >> 4, tc4 = (threadIdx.x & 15) * 4;
#pragma unroll
  for (int i = 0; i < 4; ++i) {
    const int rr = tr + i * 16;
    const f32x4 v = *(const f32x4*)(ip + (size_t)(r0 + rr) * C + c0 + tc4);
#pragma unroll
    for (int j = 0; j < 4; ++j) t[tc4 + j][rr] = f2h(v[j]);
  }
  __syncthreads();
  const int oc = threadIdx.x >> 3, or8 = (threadIdx.x & 7) * 8;
#pragma unroll
  for (int i = 0; i < 2; ++i) {
    const int c = oc + i * 32;
    const us8 v = *(const us8*)&t[c][or8];
    *(us8*)(op + (size_t)(c0 + c) * R + r0 + or8) = v;
  }
}

// ---------------------------------------------------------------------------
extern "C" void kernel_launch(void* const* d_in, const int* in_sizes, int n_in,
                              void* d_out, int out_size, void* d_ws, size_t ws_size,
                              hipStream_t stream)
{
  const float* x      = (const float*)d_in[0];
  const float* gate_w = (const float*)d_in[1];
  const float* gate_b = (const float*)d_in[2];
  const float* ph_w1  = (const float*)d_in[3];
  const float* ph_b1  = (const float*)d_in[4];
  const float* ph_w2  = (const float*)d_in[5];
  const float* ph_b2  = (const float*)d_in[6];
  const float* cl_w1  = (const float*)d_in[7];
  const float* cl_b1  = (const float*)d_in[8];
  const float* cl_w2  = (const float*)d_in[9];
  const float* cl_b2  = (const float*)d_in[10];
  const float* sigs   = (const float*)d_in[11];
  const float* e_w1   = (const float*)d_in[12];
  const float* e_b1   = (const float*)d_in[13];
  const float* e_w2   = (const float*)d_in[14];
  const float* e_b2   = (const float*)d_in[15];
  float* y = (float*)d_out;
  char* ws = (char*)d_ws;

  float* eff    = (float*)(ws + 262144);
  float* wts    = (float*)(ws + 524288);
  float* pclar  = (float*)(ws + 786432);
  float* pP     = (float*)(ws + 794624);
  int*   f_part = (int*)(ws + 860160);
  unsigned short* xh  = (unsigned short*)(ws + 1048576);
  unsigned short* W1T = (unsigned short*)(ws + 17825792u);   // [E][H][D] fp16
  unsigned short* W2T = (unsigned short*)(ws + 51380224u);   // [E][O][H] fp16
  unsigned short* Hh  = (unsigned short*)(ws + 84934656u);   // [N][H] fp16

  transpose_kernel<<<dim3(32, 16, 8), 256, 0, stream>>>(e_w1, W1T, 1024, 2048);
  transpose_kernel<<<dim3(16, 32, 8), 256, 0, stream>>>(e_w2, W2T, 2048, 1024);
  gating_kernel<<<2048, 256, 0, stream>>>(x, gate_w, gate_b, ph_w1, ph_b1, ph_w2, ph_b2,
                                          cl_w1, cl_b1, cl_w2, cl_b2, sigs,
                                          xh, eff, pclar, pP);
  weights_kernel<<<32, 256, 0, stream>>>(eff, pclar, wts, f_part);
  lb_kernel<<<1, 256, 0, stream>>>(pP, f_part, y + (size_t)8192 * 1024);
  yinit_kernel<<<8192, 256, 0, stream>>>(wts, e_b2, y);

  for (int e2 = 0; e2 < 8; ++e2) {
    gemm_kernel<1><<<dim3(16, 64), 256, 0, stream>>>(
        xh, W1T + (size_t)e2 * HDIM * DIM, N_TOK, HDIM, DIM,
        e_b1 + e2 * HDIM, Hh, nullptr, 0, nullptr);
    gemm_kernel<2><<<dim3(8, 64), 256, 0, stream>>>(
        Hh, W2T + (size_t)e2 * ODIM * HDIM, N_TOK, ODIM, HDIM,
        nullptr, nullptr, wts, e2, y);
  }
}